// Round 9
// baseline (458.475 us; speedup 1.0000x reference)
//
#include <hip/hip_runtime.h>
#include <hip/hip_fp16.h>
#include <cstdint>
#include <cstddef>

#define F_IN 128
#define NOUT 40
#define BN_EPS 1e-5f
#define RBITS 8
#define RSIZE 256           // nodes per range
#define MAXNR 512           // supports N <= 131072
#define DBINS 64            // degree-sort bins (cap 63)

typedef unsigned short u16;
typedef unsigned int u32;
typedef __attribute__((ext_vector_type(8))) short short8v;  // 8 bf16 (4 VGPR)
typedef __attribute__((ext_vector_type(4))) float f32x4;

static inline int ceil_div_l(long a, long b){ return (int)((a + b - 1) / b); }

__device__ __forceinline__ float b2f(u16 h){
  union { u32 u; float f; } v; v.u = ((u32)h) << 16; return v.f;
}
__device__ __forceinline__ u16 f2b(float x){
  union { float f; u32 u; } v; v.f = x;
  u32 r = v.u + 0x7FFFu + ((v.u >> 16) & 1u);
  return (u16)(r >> 16);
}
__device__ __forceinline__ float h2f_bits(u32 bits){   // low 15/16 bits = fp16
  return __half2float(__ushort_as_half((u16)bits));
}
// accumulate 16 sliced cols (2 x uint4 of bf16) with weight w
__device__ __forceinline__ void accS(float* a, uint4 p, uint4 q, float w){
  a[0] = fmaf(b2f((u16)p.x),         w, a[0]);
  a[1] = fmaf(b2f((u16)(p.x >> 16)), w, a[1]);
  a[2] = fmaf(b2f((u16)p.y),         w, a[2]);
  a[3] = fmaf(b2f((u16)(p.y >> 16)), w, a[3]);
  a[4] = fmaf(b2f((u16)p.z),         w, a[4]);
  a[5] = fmaf(b2f((u16)(p.z >> 16)), w, a[5]);
  a[6] = fmaf(b2f((u16)p.w),         w, a[6]);
  a[7] = fmaf(b2f((u16)(p.w >> 16)), w, a[7]);
  a[8]  = fmaf(b2f((u16)q.x),         w, a[8]);
  a[9]  = fmaf(b2f((u16)(q.x >> 16)), w, a[9]);
  a[10] = fmaf(b2f((u16)q.y),         w, a[10]);
  a[11] = fmaf(b2f((u16)(q.y >> 16)), w, a[11]);
  a[12] = fmaf(b2f((u16)q.z),         w, a[12]);
  a[13] = fmaf(b2f((u16)(q.z >> 16)), w, a[13]);
  a[14] = fmaf(b2f((u16)q.w),         w, a[14]);
  a[15] = fmaf(b2f((u16)(q.w >> 16)), w, a[15]);
}
__device__ __forceinline__ void acc4(float* acc, uint2 u, float w){
  acc[0] = fmaf(b2f((u16)u.x),         w, acc[0]);
  acc[1] = fmaf(b2f((u16)(u.x >> 16)), w, acc[1]);
  acc[2] = fmaf(b2f((u16)u.y),         w, acc[2]);
  acc[3] = fmaf(b2f((u16)(u.y >> 16)), w, acc[3]);
}

// ---------- A1: per-range edge counts (LDS histogram) ----------
__global__ void k_rangecount(const int* __restrict__ dst, int* __restrict__ rangecnt,
                             int E, int NR, int chunk){
  __shared__ u32 hist[MAXNR];
  for (int i = threadIdx.x; i < NR; i += 256) hist[i] = 0;
  __syncthreads();
  int s = blockIdx.x * chunk;
  int e_end = min(s + chunk, E);
  for (int e = s + threadIdx.x; e < e_end; e += 256)
    atomicAdd(&hist[(u32)dst[e] >> RBITS], 1u);
  __syncthreads();
  for (int i = threadIdx.x; i < NR; i += 256){
    u32 h = hist[i];
    if (h) atomicAdd((u32*)&rangecnt[i], h);
  }
}

// ---------- A2: exclusive scan of range counts ----------
__global__ void k_rangescan(const int* __restrict__ rangecnt, int* __restrict__ rangebase,
                            int NR){
  __shared__ int s[MAXNR];
  int t = threadIdx.x;
  if (t < NR) s[t] = rangecnt[t];
  __syncthreads();
  if (t == 0){
    int acc = 0;
    for (int i = 0; i < NR; i++){ int v = s[i]; s[i] = acc; acc += v; }
  }
  __syncthreads();
  if (t < NR) rangebase[t] = s[t];
}

// ---------- A3: partition edges into per-range segments (packed u32) ----------
__global__ void k_partition(const int* __restrict__ src, const int* __restrict__ dst,
                            const int* __restrict__ rangebase, int* __restrict__ rangefill,
                            u32* __restrict__ part, int E, int NR, int chunk){
  __shared__ u32 hist[MAXNR];
  __shared__ u32 lbase[MAXNR];
  for (int i = threadIdx.x; i < NR; i += 256) hist[i] = 0;
  __syncthreads();
  int s0 = blockIdx.x * chunk;
  int e_end = min(s0 + chunk, E);
  for (int e = s0 + threadIdx.x; e < e_end; e += 256)
    atomicAdd(&hist[(u32)dst[e] >> RBITS], 1u);
  __syncthreads();
  for (int i = threadIdx.x; i < NR; i += 256){
    u32 h = hist[i];
    u32 b = h ? (u32)atomicAdd((u32*)&rangefill[i], h) : 0u;
    lbase[i] = (u32)rangebase[i] + b;
    hist[i] = 0;                       // reuse as local fill
  }
  __syncthreads();
  for (int e = s0 + threadIdx.x; e < e_end; e += 256){
    u32 d = (u32)dst[e];
    u32 r = d >> RBITS;
    u32 pos = lbase[r] + atomicAdd(&hist[r], 1u);
    part[pos] = (u32)src[e] | ((d & (RSIZE - 1)) << 17);
  }
}

// ---------- B: per-range CSR build + meta/dinv + degree histogram (LDS atomics) ----------
__global__ void k_build(const u32* __restrict__ part, const int* __restrict__ rangecnt,
                        const int* __restrict__ rangebase, int4* __restrict__ meta,
                        float* __restrict__ dinv, int* __restrict__ csr,
                        int* __restrict__ dhist, int n){
  __shared__ int hist[RSIZE];
  __shared__ int scanx[RSIZE];
  __shared__ int fill[RSIZE];
  __shared__ int ldh[DBINS];
  int r = blockIdx.x;
  int ne = rangecnt[r], base = rangebase[r];
  int t = threadIdx.x;
  hist[t] = 0;
  if (t < DBINS) ldh[t] = 0;
  __syncthreads();
  for (int i = t; i < ne; i += 256) atomicAdd(&hist[part[base + i] >> 17], 1);
  __syncthreads();
  int v = hist[t];
  scanx[t] = v;
  __syncthreads();
  for (int o = 1; o < 256; o <<= 1){
    int tv = (t >= o) ? scanx[t - o] : 0;
    __syncthreads();
    scanx[t] += tv;
    __syncthreads();
  }
  int excl = scanx[t] - v;
  int node = (r << RBITS) + t;
  if (node < n){
    float di = rsqrtf(1.0f + (float)v);
    meta[node] = make_int4(base + excl, v, __float_as_int(di), 0);
    dinv[node] = di;
    atomicAdd(&ldh[min(v, DBINS - 1)], 1);   // fused degree histogram
  }
  fill[t] = 0;
  scanx[t] = excl;
  __syncthreads();
  for (int i = t; i < ne; i += 256){
    u32 p = part[base + i];
    int dl = (int)(p >> 17);
    int pos = scanx[dl] + atomicAdd(&fill[dl], 1);
    csr[base + pos] = (int)(p & 0x1FFFFu);
  }
  if (t < DBINS && ldh[t]) atomicAdd(&dhist[t], ldh[t]);
}

// ---------- scan degree bins: node base + edge base per bin ----------
__global__ void k_scan2(const int* __restrict__ dhist, int* __restrict__ dbase,
                        int* __restrict__ ebase, int* __restrict__ ecapfill){
  if (threadIdx.x == 0 && blockIdx.x == 0){
    int na = 0; long ea = 0;
    for (int b = 0; b < DBINS; b++){
      dbase[b] = na; ebase[b] = (int)ea;
      na += dhist[b]; ea += (long)dhist[b] * b;
    }
    ecapfill[0] = (int)ebase[DBINS - 1] + 0;   // cap-bin edges allocated upward from here
    // note: exact-bin edges total == ebase[63]; cap edges fill the remainder of E
    ecapfill[0] = ebase[DBINS - 1];
  }
}

// ---------- degree-sorted placement: pm[pos] = (prowstart, node, num<<16|fp16(dinv), oldbeg) ----------
__global__ void k_degplace(const int4* __restrict__ meta, const int* __restrict__ dbase,
                           const int* __restrict__ ebase, int* __restrict__ dfill,
                           int* __restrict__ ecapfill, uint4* __restrict__ pm, int n){
  __shared__ int h[DBINS], lbase[DBINS];
  if (threadIdx.x < DBINS) h[threadIdx.x] = 0;
  __syncthreads();
  int i = blockIdx.x * 256 + threadIdx.x;
  int d = 0; int4 m = make_int4(0,0,0,0);
  if (i < n){
    m = meta[i];
    d = min(m.y, DBINS - 1);
    atomicAdd(&h[d], 1);
  }
  __syncthreads();
  if (threadIdx.x < DBINS){
    int c = h[threadIdx.x];
    lbase[threadIdx.x] = c ? dbase[threadIdx.x] + atomicAdd(&dfill[threadIdx.x], c) : 0;
    h[threadIdx.x] = 0;
  }
  __syncthreads();
  if (i < n){
    int pos = lbase[d] + atomicAdd(&h[d], 1);
    u32 prow;
    if (d < DBINS - 1) prow = (u32)(ebase[d] + (pos - dbase[d]) * d);
    else               prow = (u32)atomicAdd(ecapfill, m.y);
    float di = __int_as_float(m.z);
    u16 hb = __half_as_ushort(__float2half(di));
    pm[pos] = make_uint4(prow, (u32)i, ((u32)m.y << 16) | hb, (u32)m.x);
  }
}

// ---------- permuted packed edge list: ewp[prow+j] = fp16(dinv[src])<<17 | src ----------
__global__ void k_makeewp(const uint4* __restrict__ pm, const int* __restrict__ csr,
                          const float* __restrict__ dinv, u32* __restrict__ ewp, int n){
  int g = blockIdx.x * 256 + threadIdx.x;
  if (g >= n) return;
  uint4 m = pm[g];
  int prow = (int)m.x, num = (int)(m.z >> 16), oldbeg = (int)m.w;
  for (int j = 0; j < num; j++){
    int s = csr[oldbeg + j];
    u32 hb = (u32)__half_as_ushort(__float2half(dinv[s]));
    ewp[prow + j] = (u32)s | (hb << 17);
  }
}

// ---------- MFMA GEMM: 128-row x COLS tile, K=128, bf16 out, fp32 acc ----------
// XBF: input is bf16 in SLICED layout [8][n][16]; else fp32 row-major [n][128].
// SLOUT: output sliced [8][n][16]; else row-major [n][ldY].
// BN: per-block prelude computes scale/shift from 8-striped raw sums (fused bn_fin).
template<int COLS, bool XBF, bool BN, bool SLOUT>
__launch_bounds__(256, 2)
__global__ void k_gemm_mfma(const void* __restrict__ Xv, const float* __restrict__ W,
                            int ldW, int wcols,
                            const float* __restrict__ bn_sum, const float* __restrict__ bn_sq,
                            const float* __restrict__ g, const float* __restrict__ beta,
                            u16* __restrict__ Y, int ldY, int col_off, int n, int ntiles,
                            size_t nsl){
  constexpr int NT = COLS / 16;          // col tiles per wave
  extern __shared__ u16 dyn_lds[];
  u16* Xl = dyn_lds;                     // [128][136]
  u16* Wt = dyn_lds + 128 * 136;         // [COLS][136]
  __shared__ float sc_l[128], sh_l[128];

  const int tid  = threadIdx.x;
  const int lane = tid & 63;
  const int wv   = tid >> 6;             // wave 0..3 -> rows wv*32..wv*32+31

  if (BN){
    if (tid < 128){
      float s = 0.f, q = 0.f;
      #pragma unroll
      for (int k = 0; k < 8; k++){ s += bn_sum[(k << 7) + tid]; q += bn_sq[(k << 7) + tid]; }
      float invn = 1.0f / (float)n;
      float mu  = s * invn;
      float var = q * invn - mu * mu;
      var = var > 0.f ? var : 0.f;
      float sc = g[tid] * rsqrtf(var + BN_EPS);
      sc_l[tid] = sc;
      sh_l[tid] = beta[tid] - mu * sc;
    }
    __syncthreads();
  }

  // stage W transposed (zero-pad cols >= wcols); wcols is a multiple of 4
  const int wf4 = wcols >> 2;
  for (int idx = tid; idx < 128 * (COLS >> 2); idx += 256){
    int k  = idx / (COLS >> 2);
    int c4 = idx % (COLS >> 2);
    float4 v = make_float4(0.f, 0.f, 0.f, 0.f);
    if (c4 < wf4) v = *(const float4*)(W + (size_t)k * ldW + (c4 << 2));
    int c = c4 << 2;
    Wt[(c    ) * 136 + k] = f2b(v.x);
    Wt[(c + 1) * 136 + k] = f2b(v.y);
    Wt[(c + 2) * 136 + k] = f2b(v.z);
    Wt[(c + 3) * 136 + k] = f2b(v.w);
  }

  float sc8[8], sh8[8];
  if (BN){
    int c0 = (tid & 15) << 3;
    #pragma unroll
    for (int j = 0; j < 8; j++){ sc8[j] = sc_l[c0 + j]; sh8[j] = sh_l[c0 + j]; }
  }

  const int frow = lane & 15;
  const int fk   = (lane >> 4) << 3;     // 0,8,16,24

  for (int t = blockIdx.x; t < ntiles; t += gridDim.x){
    const int r0 = t << 7;
    __syncthreads();   // protects Xl (prev readers) and covers Wt on first iter
    // stage X tile (bf16, optional fused BN+ReLU)
    for (int idx = tid; idx < 128 * 16; idx += 256){
      int row = idx >> 4, c8 = idx & 15;
      int gr = r0 + row;
      float x[8];
      if (gr < n){
        if (XBF){
          const u16* p = (const u16*)Xv + (size_t)(c8 >> 1) * nsl
                         + ((size_t)gr << 4) + ((c8 & 1) << 3);
          uint4 u = *(const uint4*)p;
          x[0] = b2f((u16)u.x); x[1] = b2f((u16)(u.x >> 16));
          x[2] = b2f((u16)u.y); x[3] = b2f((u16)(u.y >> 16));
          x[4] = b2f((u16)u.z); x[5] = b2f((u16)(u.z >> 16));
          x[6] = b2f((u16)u.w); x[7] = b2f((u16)(u.w >> 16));
        } else {
          const float* p = (const float*)Xv + ((size_t)gr << 7) + (c8 << 3);
          float4 a = *(const float4*)p;
          float4 b = *(const float4*)(p + 4);
          x[0]=a.x; x[1]=a.y; x[2]=a.z; x[3]=a.w;
          x[4]=b.x; x[5]=b.y; x[6]=b.z; x[7]=b.w;
        }
        if (BN){
          #pragma unroll
          for (int j = 0; j < 8; j++)
            x[j] = fmaxf(fmaf(x[j], sc8[j], sh8[j]), 0.f);
        }
      } else {
        #pragma unroll
        for (int j = 0; j < 8; j++) x[j] = 0.f;
      }
      uint4 u;
      u.x = (u32)f2b(x[0]) | ((u32)f2b(x[1]) << 16);
      u.y = (u32)f2b(x[2]) | ((u32)f2b(x[3]) << 16);
      u.z = (u32)f2b(x[4]) | ((u32)f2b(x[5]) << 16);
      u.w = (u32)f2b(x[6]) | ((u32)f2b(x[7]) << 16);
      *(uint4*)(Xl + row * 136 + (c8 << 3)) = u;
    }
    __syncthreads();

    f32x4 acc[2][NT];
    #pragma unroll
    for (int i = 0; i < 2; i++)
      #pragma unroll
      for (int j = 0; j < NT; j++)
        acc[i][j] = (f32x4){0.f, 0.f, 0.f, 0.f};

    #pragma unroll
    for (int ks = 0; ks < 4; ks++){
      const int ko = (ks << 5) + fk;
      short8v a0 = *(const short8v*)(Xl + (wv * 32      + frow) * 136 + ko);
      short8v a1 = *(const short8v*)(Xl + (wv * 32 + 16 + frow) * 136 + ko);
      short8v b[NT];
      #pragma unroll
      for (int j = 0; j < NT; j++)
        b[j] = *(const short8v*)(Wt + (j * 16 + frow) * 136 + ko);
      #pragma unroll
      for (int j = 0; j < NT; j++){
        acc[0][j] = __builtin_amdgcn_mfma_f32_16x16x32_bf16(a0, b[j], acc[0][j], 0, 0, 0);
        acc[1][j] = __builtin_amdgcn_mfma_f32_16x16x32_bf16(a1, b[j], acc[1][j], 0, 0, 0);
      }
    }

    // store: D lane l -> col=l&15, rows (l>>4)*4+0..3 of each 16x16 tile
    #pragma unroll
    for (int i = 0; i < 2; i++){
      #pragma unroll
      for (int j = 0; j < NT; j++){
        int cbase = j * 16 + (lane & 15);
        int grow = r0 + wv * 32 + i * 16 + ((lane >> 4) << 2);
        if (SLOUT){
          int gcol = col_off + cbase;
          u16* yb = Y + (size_t)(gcol >> 4) * nsl + (gcol & 15);
          #pragma unroll
          for (int r = 0; r < 4; r++){
            if (grow + r < n) yb[(size_t)(grow + r) << 4] = f2b(acc[i][j][r]);
          }
        } else {
          if (cbase < wcols){
            #pragma unroll
            for (int r = 0; r < 4; r++){
              if (grow + r < n)
                Y[(size_t)(grow + r) * ldY + col_off + cbase] = f2b(acc[i][j][r]);
            }
          }
        }
      }
    }
  }
}

// ---------- sliced aggregation: 1 thread per (node x 16-col slice), slice pinned to XCD ----------
__launch_bounds__(256)
__global__ void k_agg128s(const u16* __restrict__ H, u16* __restrict__ Y,
                          const uint4* __restrict__ pm, const u32* __restrict__ ewp,
                          int n, size_t nsl){
  const int cs = blockIdx.x & 7;                       // slice -> XCD (round-robin dispatch)
  const int g  = ((blockIdx.x >> 3) << 8) + threadIdx.x;
  if (g >= n) return;
  uint4 m = pm[g];
  const int beg = (int)m.x, node = (int)m.y, num = (int)(m.z >> 16);
  const float di = h2f_bits(m.z & 0xFFFFu);
  const u16* Hs = H + (size_t)cs * nsl;
  float a[16];
  {
    const uint4* p = (const uint4*)(Hs + ((size_t)node << 4));
    uint4 u = p[0], v = p[1];
    a[0]=b2f((u16)u.x)*di; a[1]=b2f((u16)(u.x>>16))*di;
    a[2]=b2f((u16)u.y)*di; a[3]=b2f((u16)(u.y>>16))*di;
    a[4]=b2f((u16)u.z)*di; a[5]=b2f((u16)(u.z>>16))*di;
    a[6]=b2f((u16)u.w)*di; a[7]=b2f((u16)(u.w>>16))*di;
    a[8]=b2f((u16)v.x)*di;  a[9]=b2f((u16)(v.x>>16))*di;
    a[10]=b2f((u16)v.y)*di; a[11]=b2f((u16)(v.y>>16))*di;
    a[12]=b2f((u16)v.z)*di; a[13]=b2f((u16)(v.z>>16))*di;
    a[14]=b2f((u16)v.w)*di; a[15]=b2f((u16)(v.w>>16))*di;
  }
  int i = 0;
  for (; i + 4 <= num; i += 4){
    u32 e0 = ewp[beg + i], e1 = ewp[beg + i + 1];
    u32 e2 = ewp[beg + i + 2], e3 = ewp[beg + i + 3];
    const uint4* p0 = (const uint4*)(Hs + ((size_t)(e0 & 0x1FFFFu) << 4));
    const uint4* p1 = (const uint4*)(Hs + ((size_t)(e1 & 0x1FFFFu) << 4));
    const uint4* p2 = (const uint4*)(Hs + ((size_t)(e2 & 0x1FFFFu) << 4));
    const uint4* p3 = (const uint4*)(Hs + ((size_t)(e3 & 0x1FFFFu) << 4));
    uint4 u0 = p0[0], v0 = p0[1];
    uint4 u1 = p1[0], v1 = p1[1];
    uint4 u2 = p2[0], v2 = p2[1];
    uint4 u3 = p3[0], v3 = p3[1];
    accS(a, u0, v0, h2f_bits(e0 >> 17));
    accS(a, u1, v1, h2f_bits(e1 >> 17));
    accS(a, u2, v2, h2f_bits(e2 >> 17));
    accS(a, u3, v3, h2f_bits(e3 >> 17));
  }
  for (; i < num; i++){
    u32 e = ewp[beg + i];
    const uint4* p = (const uint4*)(Hs + ((size_t)(e & 0x1FFFFu) << 4));
    accS(a, p[0], p[1], h2f_bits(e >> 17));
  }
  uint4 o0, o1;
  o0.x = (u32)f2b(a[0]*di)  | ((u32)f2b(a[1]*di)  << 16);
  o0.y = (u32)f2b(a[2]*di)  | ((u32)f2b(a[3]*di)  << 16);
  o0.z = (u32)f2b(a[4]*di)  | ((u32)f2b(a[5]*di)  << 16);
  o0.w = (u32)f2b(a[6]*di)  | ((u32)f2b(a[7]*di)  << 16);
  o1.x = (u32)f2b(a[8]*di)  | ((u32)f2b(a[9]*di)  << 16);
  o1.y = (u32)f2b(a[10]*di) | ((u32)f2b(a[11]*di) << 16);
  o1.z = (u32)f2b(a[12]*di) | ((u32)f2b(a[13]*di) << 16);
  o1.w = (u32)f2b(a[14]*di) | ((u32)f2b(a[15]*di) << 16);
  uint4* yp = (uint4*)(Y + (size_t)cs * nsl + ((size_t)node << 4));
  yp[0] = o0; yp[1] = o1;
}

// ---------- agg40: row-major H40 [n][40] bf16 -> fp32 out + bias ----------
__global__ void k_agg40(const u16* __restrict__ H, const float* __restrict__ bout,
                        float* __restrict__ Y, const uint4* __restrict__ pm,
                        const u32* __restrict__ ewp, int n){
  int t = blockIdx.x * 256 + threadIdx.x;
  int g = t >> 4, c4 = t & 15;
  if (g >= n || c4 >= 10) return;
  uint4 m = pm[g];
  const int beg = (int)m.x, node = (int)m.y, num = (int)(m.z >> 16);
  const float di = h2f_bits(m.z & 0xFFFFu);
  float acc[4];
  {
    uint2 u = *(const uint2*)(H + (size_t)node * NOUT + (c4 << 2));
    acc[0] = b2f((u16)u.x) * di; acc[1] = b2f((u16)(u.x >> 16)) * di;
    acc[2] = b2f((u16)u.y) * di; acc[3] = b2f((u16)(u.y >> 16)) * di;
  }
  int i = 0;
  for (; i + 4 <= num; i += 4){
    u32 e0 = ewp[beg + i], e1 = ewp[beg + i + 1];
    u32 e2 = ewp[beg + i + 2], e3 = ewp[beg + i + 3];
    uint2 a0 = *(const uint2*)(H + (size_t)(e0 & 0x1FFFFu) * NOUT + (c4 << 2));
    uint2 a1 = *(const uint2*)(H + (size_t)(e1 & 0x1FFFFu) * NOUT + (c4 << 2));
    uint2 a2 = *(const uint2*)(H + (size_t)(e2 & 0x1FFFFu) * NOUT + (c4 << 2));
    uint2 a3 = *(const uint2*)(H + (size_t)(e3 & 0x1FFFFu) * NOUT + (c4 << 2));
    acc4(acc, a0, h2f_bits(e0 >> 17));
    acc4(acc, a1, h2f_bits(e1 >> 17));
    acc4(acc, a2, h2f_bits(e2 >> 17));
    acc4(acc, a3, h2f_bits(e3 >> 17));
  }
  for (; i < num; i++){
    u32 e = ewp[beg + i];
    uint2 u = *(const uint2*)(H + (size_t)(e & 0x1FFFFu) * NOUT + (c4 << 2));
    acc4(acc, u, h2f_bits(e >> 17));
  }
  float4 bb = *(const float4*)(bout + (c4 << 2));
  float4 o;
  o.x = fmaf(acc[0], di, bb.x); o.y = fmaf(acc[1], di, bb.y);
  o.z = fmaf(acc[2], di, bb.z); o.w = fmaf(acc[3], di, bb.w);
  *(float4*)(Y + (size_t)node * NOUT + (c4 << 2)) = o;
}

// ---------- BatchNorm stats (sliced bf16 input, uint4 loads, 8-striped output) ----------
__global__ void k_bn_stats(const u16* __restrict__ X, float* __restrict__ sum8,
                           float* __restrict__ sq8, int n, size_t nsl){
  const int tid = threadIdx.x;
  const int c8 = tid & 15, rl = tid >> 4;
  const u16* Xs = X + (size_t)(c8 >> 1) * nsl + ((c8 & 1) << 3);
  float s[8] = {0,0,0,0,0,0,0,0}, q[8] = {0,0,0,0,0,0,0,0};
  for (int r = blockIdx.x * 16 + rl; r < n; r += gridDim.x * 16){
    uint4 u = *(const uint4*)(Xs + ((size_t)r << 4));
    float x0 = b2f((u16)u.x), x1 = b2f((u16)(u.x >> 16));
    float x2 = b2f((u16)u.y), x3 = b2f((u16)(u.y >> 16));
    float x4 = b2f((u16)u.z), x5 = b2f((u16)(u.z >> 16));
    float x6 = b2f((u16)u.w), x7 = b2f((u16)(u.w >> 16));
    s[0]+=x0; s[1]+=x1; s[2]+=x2; s[3]+=x3; s[4]+=x4; s[5]+=x5; s[6]+=x6; s[7]+=x7;
    q[0]=fmaf(x0,x0,q[0]); q[1]=fmaf(x1,x1,q[1]); q[2]=fmaf(x2,x2,q[2]); q[3]=fmaf(x3,x3,q[3]);
    q[4]=fmaf(x4,x4,q[4]); q[5]=fmaf(x5,x5,q[5]); q[6]=fmaf(x6,x6,q[6]); q[7]=fmaf(x7,x7,q[7]);
  }
  __shared__ float ls[256 * 8];
  const int sb = (blockIdx.x & 7) << 7;
  #pragma unroll
  for (int j = 0; j < 8; j++) ls[tid * 8 + j] = s[j];
  __syncthreads();
  if (tid < 128){
    float acc = 0.f;
    #pragma unroll
    for (int k = 0; k < 16; k++) acc += ls[(k << 7) + tid];
    atomicAdd(&sum8[sb + tid], acc);
  }
  __syncthreads();
  #pragma unroll
  for (int j = 0; j < 8; j++) ls[tid * 8 + j] = q[j];
  __syncthreads();
  if (tid < 128){
    float acc = 0.f;
    #pragma unroll
    for (int k = 0; k < 16; k++) acc += ls[(k << 7) + tid];
    atomicAdd(&sq8[sb + tid], acc);
  }
}

// ---------- launch ----------
extern "C" void kernel_launch(void* const* d_in, const int* in_sizes, int n_in,
                              void* d_out, int out_size, void* d_ws, size_t ws_size,
                              hipStream_t stream) {
  const float* x0        = (const float*)d_in[0];
  const float* x1        = (const float*)d_in[1];
  const int*   ei        = (const int*)  d_in[2];
  const float* W_init    = (const float*)d_in[3];
  const float* g_init    = (const float*)d_in[5];
  const float* beta_init = (const float*)d_in[6];
  const float* W_mid     = (const float*)d_in[7];
  const float* g_mid     = (const float*)d_in[9];
  const float* beta_mid  = (const float*)d_in[10];
  const float* W_out     = (const float*)d_in[11];
  const float* b_out     = (const float*)d_in[12];

  int N = in_sizes[0] / F_IN;
  int E = in_sizes[2] / 2;
  const int* esrc = ei;
  const int* edst = ei + E;
  int NR = (N + RSIZE - 1) >> RBITS;

  char* w = (char*)d_ws;
  size_t off = 0;
  auto take = [&](size_t bytes) -> char* {
    char* p = w + off;
    off = (off + bytes + 255) & ~(size_t)255;
    return p;
  };
  float* dinv      = (float*)take((size_t)N * 4);
  int4*  meta      = (int4*) take((size_t)N * 16);
  uint4* pm        = (uint4*)take((size_t)N * 16);
  // single zeroed block: rangecnt(512)|rangefill(512)|dhist(64)|dfill(64)|stats(4096)
  int*   zeroblk   = (int*)  take((size_t)5248 * 4);
  int*   rangecnt  = zeroblk;
  int*   rangefill = zeroblk + 512;
  int*   dhist     = zeroblk + 1024;
  int*   dfill     = zeroblk + 1088;
  float* stats     = (float*)(zeroblk + 1152);
  int*   rangebase = (int*)  take((size_t)MAXNR * 4);
  int*   dbase     = (int*)  take((size_t)DBINS * 4);
  int*   ebase     = (int*)  take((size_t)DBINS * 4);
  int*   ecapfill  = (int*)  take(64);
  u32*   part      = (u32*)  take((size_t)E * 4);
  int*   csr       = (int*)  take((size_t)E * 4);
  u32*   ewp       = (u32*)  take((size_t)E * 4);
  u16*   A         = (u16*)  take((size_t)N * 128 * 2);   // sliced [8][N][16] (or [N][40] for layer3)
  u16*   B         = (u16*)  take((size_t)N * 128 * 2);   // sliced [8][N][16]
  (void)ws_size; (void)n_in; (void)out_size;

  float* sum1 = stats;           // 8x128
  float* sq1  = stats + 1024;
  float* sum2 = stats + 2048;
  float* sq2  = stats + 3072;

  hipMemsetAsync(zeroblk, 0, (size_t)5248 * 4, stream);

  // CSR build via range partition (no global per-edge atomics)
  const int PB = 512;
  const int chunk = ceil_div_l(E, PB);
  const int NBn = ceil_div_l(N, 256);
  k_rangecount<<<PB, 256, 0, stream>>>(edst, rangecnt, E, NR, chunk);
  k_rangescan <<<1, MAXNR, 0, stream>>>(rangecnt, rangebase, NR);
  k_partition <<<PB, 256, 0, stream>>>(esrc, edst, rangebase, rangefill, part, E, NR, chunk);
  k_build     <<<NR, RSIZE, 0, stream>>>(part, rangecnt, rangebase, meta, dinv, csr, dhist, N);
  k_scan2     <<<1, 64, 0, stream>>>(dhist, dbase, ebase, ecapfill);
  k_degplace  <<<NBn, 256, 0, stream>>>(meta, dbase, ebase, dfill, ecapfill, pm, N);
  k_makeewp   <<<NBn, 256, 0, stream>>>(pm, csr, dinv, ewp, N);

  const int ntiles = ceil_div_l(N, 128);
  const size_t nsl = (size_t)N * 16;          // u16 elems per slice
  const int AGB8 = 8 * ceil_div_l(N, 256);    // sliced agg blocks
  const int AGB  = ceil_div_l((long)N * 16, 256);
  const size_t lds64  = (size_t)(128 * 136 + 64  * 136) * 2;  // 52224 B
  const size_t lds128 = (size_t)(128 * 136 + 128 * 136) * 2;  // 69632 B

  // layer 1: two branch GEMMs into concat sliced layout
  k_gemm_mfma<64,false,false,true><<<768,256,lds64,stream>>>(x0, W_init,          64, 64,
      nullptr, nullptr, nullptr, nullptr, A, 0,  0, N, ntiles, nsl);
  k_gemm_mfma<64,false,false,true><<<768,256,lds64,stream>>>(x1, W_init + 128*64, 64, 64,
      nullptr, nullptr, nullptr, nullptr, A, 0, 64, N, ntiles, nsl);
  k_agg128s<<<AGB8,256,0,stream>>>(A, B, pm, ewp, N, nsl);
  k_bn_stats<<<512,256,0,stream>>>(B, sum1, sq1, N, nsl);

  // layer 2: single 128-col MFMA GEMM (bn_fin + BN1 + ReLU fused)
  k_gemm_mfma<128,true,true,true><<<512,256,lds128,stream>>>(B, W_mid, 128, 128,
      sum1, sq1, g_init, beta_init, A, 0, 0, N, ntiles, nsl);
  k_agg128s<<<AGB8,256,0,stream>>>(A, B, pm, ewp, N, nsl);
  k_bn_stats<<<512,256,0,stream>>>(B, sum2, sq2, N, nsl);

  // layer 3: bn_fin + BN2 + ReLU fused; row-major [N][40] bf16 out
  k_gemm_mfma<64,true,true,false><<<768,256,lds64,stream>>>(B, W_out, 40, 40,
      sum2, sq2, g_mid, beta_mid, A, 40, 0, N, ntiles, nsl);
  k_agg40<<<AGB,256,0,stream>>>(A, b_out, (float*)d_out, pm, ewp, N);
}

// Round 10
// 352.829 us; speedup vs baseline: 1.2994x; 1.2994x over previous
//
#include <hip/hip_runtime.h>
#include <hip/hip_fp16.h>
#include <cstdint>
#include <cstddef>

#define F_IN 128
#define NOUT 40
#define BN_EPS 1e-5f
#define RBITS 8
#define RSIZE 256           // nodes per range
#define MAXNR 512           // supports N <= 131072
#define DBINS 64            // degree-sort bins (cap 63)

typedef unsigned short u16;
typedef unsigned int u32;
typedef __attribute__((ext_vector_type(8))) short short8v;  // 8 bf16 (4 VGPR)
typedef __attribute__((ext_vector_type(4))) float f32x4;

static inline int ceil_div_l(long a, long b){ return (int)((a + b - 1) / b); }

__device__ __forceinline__ float b2f(u16 h){
  union { u32 u; float f; } v; v.u = ((u32)h) << 16; return v.f;
}
__device__ __forceinline__ u16 f2b(float x){
  union { float f; u32 u; } v; v.f = x;
  u32 r = v.u + 0x7FFFu + ((v.u >> 16) & 1u);
  return (u16)(r >> 16);
}
__device__ __forceinline__ float h2f_bits(u32 bits){   // low 15 bits of fp16 (sign=0)
  return __half2float(__ushort_as_half((u16)bits));
}
__device__ __forceinline__ void acc8(float* acc, uint4 u, float w){
  acc[0] = fmaf(b2f((u16)u.x),         w, acc[0]);
  acc[1] = fmaf(b2f((u16)(u.x >> 16)), w, acc[1]);
  acc[2] = fmaf(b2f((u16)u.y),         w, acc[2]);
  acc[3] = fmaf(b2f((u16)(u.y >> 16)), w, acc[3]);
  acc[4] = fmaf(b2f((u16)u.z),         w, acc[4]);
  acc[5] = fmaf(b2f((u16)(u.z >> 16)), w, acc[5]);
  acc[6] = fmaf(b2f((u16)u.w),         w, acc[6]);
  acc[7] = fmaf(b2f((u16)(u.w >> 16)), w, acc[7]);
}
__device__ __forceinline__ void acc4(float* acc, uint2 u, float w){
  acc[0] = fmaf(b2f((u16)u.x),         w, acc[0]);
  acc[1] = fmaf(b2f((u16)(u.x >> 16)), w, acc[1]);
  acc[2] = fmaf(b2f((u16)u.y),         w, acc[2]);
  acc[3] = fmaf(b2f((u16)(u.y >> 16)), w, acc[3]);
}

// ---------- A1: per-range edge counts (LDS histogram) ----------
__global__ void k_rangecount(const int* __restrict__ dst, int* __restrict__ rangecnt,
                             int E, int NR, int chunk){
  __shared__ u32 hist[MAXNR];
  for (int i = threadIdx.x; i < NR; i += 256) hist[i] = 0;
  __syncthreads();
  int s = blockIdx.x * chunk;
  int e_end = min(s + chunk, E);
  for (int e = s + threadIdx.x; e < e_end; e += 256)
    atomicAdd(&hist[(u32)dst[e] >> RBITS], 1u);
  __syncthreads();
  for (int i = threadIdx.x; i < NR; i += 256){
    u32 h = hist[i];
    if (h) atomicAdd((u32*)&rangecnt[i], h);
  }
}

// ---------- A2: exclusive scan of range counts ----------
__global__ void k_rangescan(const int* __restrict__ rangecnt, int* __restrict__ rangebase,
                            int NR){
  __shared__ int s[MAXNR];
  int t = threadIdx.x;
  if (t < NR) s[t] = rangecnt[t];
  __syncthreads();
  if (t == 0){
    int acc = 0;
    for (int i = 0; i < NR; i++){ int v = s[i]; s[i] = acc; acc += v; }
  }
  __syncthreads();
  if (t < NR) rangebase[t] = s[t];
}

// ---------- A3: partition edges into per-range segments (packed u32) ----------
__global__ void k_partition(const int* __restrict__ src, const int* __restrict__ dst,
                            const int* __restrict__ rangebase, int* __restrict__ rangefill,
                            u32* __restrict__ part, int E, int NR, int chunk){
  __shared__ u32 hist[MAXNR];
  __shared__ u32 lbase[MAXNR];
  for (int i = threadIdx.x; i < NR; i += 256) hist[i] = 0;
  __syncthreads();
  int s0 = blockIdx.x * chunk;
  int e_end = min(s0 + chunk, E);
  for (int e = s0 + threadIdx.x; e < e_end; e += 256)
    atomicAdd(&hist[(u32)dst[e] >> RBITS], 1u);
  __syncthreads();
  for (int i = threadIdx.x; i < NR; i += 256){
    u32 h = hist[i];
    u32 b = h ? (u32)atomicAdd((u32*)&rangefill[i], h) : 0u;
    lbase[i] = (u32)rangebase[i] + b;
    hist[i] = 0;                       // reuse as local fill
  }
  __syncthreads();
  for (int e = s0 + threadIdx.x; e < e_end; e += 256){
    u32 d = (u32)dst[e];
    u32 r = d >> RBITS;
    u32 pos = lbase[r] + atomicAdd(&hist[r], 1u);
    part[pos] = (u32)src[e] | ((d & (RSIZE - 1)) << 17);
  }
}

// ---------- B: per-range CSR build + meta/dinv + degree histogram (LDS atomics) ----------
__global__ void k_build(const u32* __restrict__ part, const int* __restrict__ rangecnt,
                        const int* __restrict__ rangebase, int4* __restrict__ meta,
                        float* __restrict__ dinv, int* __restrict__ csr,
                        int* __restrict__ dhist, int n){
  __shared__ int hist[RSIZE];
  __shared__ int scanx[RSIZE];
  __shared__ int fill[RSIZE];
  __shared__ int ldh[DBINS];
  int r = blockIdx.x;
  int ne = rangecnt[r], base = rangebase[r];
  int t = threadIdx.x;
  hist[t] = 0;
  if (t < DBINS) ldh[t] = 0;
  __syncthreads();
  for (int i = t; i < ne; i += 256) atomicAdd(&hist[part[base + i] >> 17], 1);
  __syncthreads();
  int v = hist[t];
  scanx[t] = v;
  __syncthreads();
  for (int o = 1; o < 256; o <<= 1){
    int tv = (t >= o) ? scanx[t - o] : 0;
    __syncthreads();
    scanx[t] += tv;
    __syncthreads();
  }
  int excl = scanx[t] - v;
  int node = (r << RBITS) + t;
  if (node < n){
    float di = rsqrtf(1.0f + (float)v);
    meta[node] = make_int4(base + excl, v, __float_as_int(di), 0);
    dinv[node] = di;
    atomicAdd(&ldh[min(v, DBINS - 1)], 1);   // fused degree histogram
  }
  fill[t] = 0;
  scanx[t] = excl;
  __syncthreads();
  for (int i = t; i < ne; i += 256){
    u32 p = part[base + i];
    int dl = (int)(p >> 17);
    int pos = scanx[dl] + atomicAdd(&fill[dl], 1);
    csr[base + pos] = (int)(p & 0x1FFFFu);
  }
  if (t < DBINS && ldh[t]) atomicAdd(&dhist[t], ldh[t]);
}

// ---------- scan degree bins: node base + edge base per bin ----------
__global__ void k_scan2(const int* __restrict__ dhist, int* __restrict__ dbase,
                        int* __restrict__ ebase, int* __restrict__ ecapfill){
  if (threadIdx.x == 0 && blockIdx.x == 0){
    int na = 0; long ea = 0;
    for (int b = 0; b < DBINS; b++){
      dbase[b] = na; ebase[b] = (int)ea;
      na += dhist[b]; ea += (long)dhist[b] * b;
    }
    ecapfill[0] = ebase[DBINS - 1];   // cap-bin edges allocated upward from here
  }
}

// ---------- degree-sorted placement: pm[pos] = (prowstart, node, num<<16|fp16(dinv), oldbeg) ----------
__global__ void k_degplace(const int4* __restrict__ meta, const int* __restrict__ dbase,
                           const int* __restrict__ ebase, int* __restrict__ dfill,
                           int* __restrict__ ecapfill, uint4* __restrict__ pm, int n){
  __shared__ int h[DBINS], lbase[DBINS];
  if (threadIdx.x < DBINS) h[threadIdx.x] = 0;
  __syncthreads();
  int i = blockIdx.x * 256 + threadIdx.x;
  int d = 0; int4 m = make_int4(0,0,0,0);
  if (i < n){
    m = meta[i];
    d = min(m.y, DBINS - 1);
    atomicAdd(&h[d], 1);
  }
  __syncthreads();
  if (threadIdx.x < DBINS){
    int c = h[threadIdx.x];
    lbase[threadIdx.x] = c ? dbase[threadIdx.x] + atomicAdd(&dfill[threadIdx.x], c) : 0;
    h[threadIdx.x] = 0;
  }
  __syncthreads();
  if (i < n){
    int pos = lbase[d] + atomicAdd(&h[d], 1);
    u32 prow;
    if (d < DBINS - 1) prow = (u32)(ebase[d] + (pos - dbase[d]) * d);
    else               prow = (u32)atomicAdd(ecapfill, m.y);
    float di = __int_as_float(m.z);
    u16 hb = __half_as_ushort(__float2half(di));
    pm[pos] = make_uint4(prow, (u32)i, ((u32)m.y << 16) | hb, (u32)m.x);
  }
}

// ---------- permuted packed edge list: ewp[prow+j] = fp16(dinv[src])<<17 | src ----------
__global__ void k_makeewp(const uint4* __restrict__ pm, const int* __restrict__ csr,
                          const float* __restrict__ dinv, u32* __restrict__ ewp, int n){
  int g = blockIdx.x * 256 + threadIdx.x;
  if (g >= n) return;
  uint4 m = pm[g];
  int prow = (int)m.x, num = (int)(m.z >> 16), oldbeg = (int)m.w;
  for (int j = 0; j < num; j++){
    int s = csr[oldbeg + j];
    u32 hb = (u32)__half_as_ushort(__float2half(dinv[s]));
    ewp[prow + j] = (u32)s | (hb << 17);
  }
}

// ---------- MFMA GEMM: 128-row x COLS tile, K=128, bf16 in/out, fp32 acc ----------
// BN=true: per-block prelude computes scale/shift from 8-striped raw sums (fused bn_fin).
template<int COLS, bool XBF, bool BN>
__launch_bounds__(256, 2)
__global__ void k_gemm_mfma(const void* __restrict__ Xv, const float* __restrict__ W,
                            int ldW, int wcols,
                            const float* __restrict__ bn_sum, const float* __restrict__ bn_sq,
                            const float* __restrict__ g, const float* __restrict__ beta,
                            u16* __restrict__ Y, int ldY, int col_off, int n, int ntiles){
  constexpr int NT = COLS / 16;          // col tiles per wave
  extern __shared__ u16 dyn_lds[];
  u16* Xl = dyn_lds;                     // [128][136]
  u16* Wt = dyn_lds + 128 * 136;         // [COLS][136]
  __shared__ float sc_l[128], sh_l[128];

  const int tid  = threadIdx.x;
  const int lane = tid & 63;
  const int wv   = tid >> 6;             // wave 0..3 -> rows wv*32..wv*32+31

  if (BN){
    if (tid < 128){
      float s = 0.f, q = 0.f;
      #pragma unroll
      for (int k = 0; k < 8; k++){ s += bn_sum[(k << 7) + tid]; q += bn_sq[(k << 7) + tid]; }
      float invn = 1.0f / (float)n;
      float mu  = s * invn;
      float var = q * invn - mu * mu;
      var = var > 0.f ? var : 0.f;
      float sc = g[tid] * rsqrtf(var + BN_EPS);
      sc_l[tid] = sc;
      sh_l[tid] = beta[tid] - mu * sc;
    }
    __syncthreads();
  }

  // stage W transposed (zero-pad cols >= wcols); wcols is a multiple of 4
  const int wf4 = wcols >> 2;
  for (int idx = tid; idx < 128 * (COLS >> 2); idx += 256){
    int k  = idx / (COLS >> 2);
    int c4 = idx % (COLS >> 2);
    float4 v = make_float4(0.f, 0.f, 0.f, 0.f);
    if (c4 < wf4) v = *(const float4*)(W + (size_t)k * ldW + (c4 << 2));
    int c = c4 << 2;
    Wt[(c    ) * 136 + k] = f2b(v.x);
    Wt[(c + 1) * 136 + k] = f2b(v.y);
    Wt[(c + 2) * 136 + k] = f2b(v.z);
    Wt[(c + 3) * 136 + k] = f2b(v.w);
  }

  float sc8[8], sh8[8];
  if (BN){
    int c0 = (tid & 15) << 3;
    #pragma unroll
    for (int j = 0; j < 8; j++){ sc8[j] = sc_l[c0 + j]; sh8[j] = sh_l[c0 + j]; }
  }

  const int frow = lane & 15;
  const int fk   = (lane >> 4) << 3;     // 0,8,16,24

  for (int t = blockIdx.x; t < ntiles; t += gridDim.x){
    const int r0 = t << 7;
    __syncthreads();   // protects Xl (prev readers) and covers Wt on first iter
    // stage X tile (bf16, optional fused BN+ReLU)
    for (int idx = tid; idx < 128 * 16; idx += 256){
      int row = idx >> 4, c8 = idx & 15;
      int gr = r0 + row;
      float x[8];
      if (gr < n){
        if (XBF){
          const u16* p = (const u16*)Xv + ((size_t)gr << 7) + (c8 << 3);
          uint4 u = *(const uint4*)p;
          x[0] = b2f((u16)u.x); x[1] = b2f((u16)(u.x >> 16));
          x[2] = b2f((u16)u.y); x[3] = b2f((u16)(u.y >> 16));
          x[4] = b2f((u16)u.z); x[5] = b2f((u16)(u.z >> 16));
          x[6] = b2f((u16)u.w); x[7] = b2f((u16)(u.w >> 16));
        } else {
          const float* p = (const float*)Xv + ((size_t)gr << 7) + (c8 << 3);
          float4 a = *(const float4*)p;
          float4 b = *(const float4*)(p + 4);
          x[0]=a.x; x[1]=a.y; x[2]=a.z; x[3]=a.w;
          x[4]=b.x; x[5]=b.y; x[6]=b.z; x[7]=b.w;
        }
        if (BN){
          #pragma unroll
          for (int j = 0; j < 8; j++)
            x[j] = fmaxf(fmaf(x[j], sc8[j], sh8[j]), 0.f);
        }
      } else {
        #pragma unroll
        for (int j = 0; j < 8; j++) x[j] = 0.f;
      }
      uint4 u;
      u.x = (u32)f2b(x[0]) | ((u32)f2b(x[1]) << 16);
      u.y = (u32)f2b(x[2]) | ((u32)f2b(x[3]) << 16);
      u.z = (u32)f2b(x[4]) | ((u32)f2b(x[5]) << 16);
      u.w = (u32)f2b(x[6]) | ((u32)f2b(x[7]) << 16);
      *(uint4*)(Xl + row * 136 + (c8 << 3)) = u;
    }
    __syncthreads();

    f32x4 acc[2][NT];
    #pragma unroll
    for (int i = 0; i < 2; i++)
      #pragma unroll
      for (int j = 0; j < NT; j++)
        acc[i][j] = (f32x4){0.f, 0.f, 0.f, 0.f};

    #pragma unroll
    for (int ks = 0; ks < 4; ks++){
      const int ko = (ks << 5) + fk;
      short8v a0 = *(const short8v*)(Xl + (wv * 32      + frow) * 136 + ko);
      short8v a1 = *(const short8v*)(Xl + (wv * 32 + 16 + frow) * 136 + ko);
      short8v b[NT];
      #pragma unroll
      for (int j = 0; j < NT; j++)
        b[j] = *(const short8v*)(Wt + (j * 16 + frow) * 136 + ko);
      #pragma unroll
      for (int j = 0; j < NT; j++){
        acc[0][j] = __builtin_amdgcn_mfma_f32_16x16x32_bf16(a0, b[j], acc[0][j], 0, 0, 0);
        acc[1][j] = __builtin_amdgcn_mfma_f32_16x16x32_bf16(a1, b[j], acc[1][j], 0, 0, 0);
      }
    }

    // store: D lane l -> col=l&15, rows (l>>4)*4+0..3 of each 16x16 tile
    #pragma unroll
    for (int i = 0; i < 2; i++){
      #pragma unroll
      for (int j = 0; j < NT; j++){
        int cbase = j * 16 + (lane & 15);
        if (cbase < wcols){
          int grow = r0 + wv * 32 + i * 16 + ((lane >> 4) << 2);
          #pragma unroll
          for (int r = 0; r < 4; r++){
            if (grow + r < n)
              Y[(size_t)(grow + r) * ldY + col_off + cbase] = f2b(acc[i][j][r]);
          }
        }
      }
    }
  }
}

// ---------- aggregation: 16 lanes/node, packed 4B edges, degree-sorted order ----------
__global__ void k_agg128(const u16* __restrict__ H, u16* __restrict__ Y,
                         const uint4* __restrict__ pm, const u32* __restrict__ ewp, int n){
  int t = blockIdx.x * 256 + threadIdx.x;
  int g = t >> 4, c8 = t & 15;
  if (g >= n) return;
  uint4 m = pm[g];
  const int beg = (int)m.x, node = (int)m.y, num = (int)(m.z >> 16);
  const float di = h2f_bits(m.z & 0xFFFFu);
  float acc[8];
  {
    uint4 u = *(const uint4*)(H + ((size_t)node << 7) + (c8 << 3));
    acc[0] = b2f((u16)u.x) * di; acc[1] = b2f((u16)(u.x >> 16)) * di;
    acc[2] = b2f((u16)u.y) * di; acc[3] = b2f((u16)(u.y >> 16)) * di;
    acc[4] = b2f((u16)u.z) * di; acc[5] = b2f((u16)(u.z >> 16)) * di;
    acc[6] = b2f((u16)u.w) * di; acc[7] = b2f((u16)(u.w >> 16)) * di;
  }
  int i = 0;
  // head: align (beg+i) to 4 for uint4 edge loads
  for (; i < num && ((beg + i) & 3); i++){
    u32 e = ewp[beg + i];
    acc8(acc, *(const uint4*)(H + ((size_t)(e & 0x1FFFFu) << 7) + (c8 << 3)), h2f_bits(e >> 17));
  }
  for (; i + 8 <= num; i += 8){
    uint4 e0 = *(const uint4*)(ewp + beg + i);
    uint4 e1 = *(const uint4*)(ewp + beg + i + 4);
    uint4 h0 = *(const uint4*)(H + ((size_t)(e0.x & 0x1FFFFu) << 7) + (c8 << 3));
    uint4 h1 = *(const uint4*)(H + ((size_t)(e0.y & 0x1FFFFu) << 7) + (c8 << 3));
    uint4 h2 = *(const uint4*)(H + ((size_t)(e0.z & 0x1FFFFu) << 7) + (c8 << 3));
    uint4 h3 = *(const uint4*)(H + ((size_t)(e0.w & 0x1FFFFu) << 7) + (c8 << 3));
    uint4 h4 = *(const uint4*)(H + ((size_t)(e1.x & 0x1FFFFu) << 7) + (c8 << 3));
    uint4 h5 = *(const uint4*)(H + ((size_t)(e1.y & 0x1FFFFu) << 7) + (c8 << 3));
    uint4 h6 = *(const uint4*)(H + ((size_t)(e1.z & 0x1FFFFu) << 7) + (c8 << 3));
    uint4 h7 = *(const uint4*)(H + ((size_t)(e1.w & 0x1FFFFu) << 7) + (c8 << 3));
    acc8(acc, h0, h2f_bits(e0.x >> 17));
    acc8(acc, h1, h2f_bits(e0.y >> 17));
    acc8(acc, h2, h2f_bits(e0.z >> 17));
    acc8(acc, h3, h2f_bits(e0.w >> 17));
    acc8(acc, h4, h2f_bits(e1.x >> 17));
    acc8(acc, h5, h2f_bits(e1.y >> 17));
    acc8(acc, h6, h2f_bits(e1.z >> 17));
    acc8(acc, h7, h2f_bits(e1.w >> 17));
  }
  if (i + 4 <= num){
    uint4 e0 = *(const uint4*)(ewp + beg + i);
    uint4 h0 = *(const uint4*)(H + ((size_t)(e0.x & 0x1FFFFu) << 7) + (c8 << 3));
    uint4 h1 = *(const uint4*)(H + ((size_t)(e0.y & 0x1FFFFu) << 7) + (c8 << 3));
    uint4 h2 = *(const uint4*)(H + ((size_t)(e0.z & 0x1FFFFu) << 7) + (c8 << 3));
    uint4 h3 = *(const uint4*)(H + ((size_t)(e0.w & 0x1FFFFu) << 7) + (c8 << 3));
    acc8(acc, h0, h2f_bits(e0.x >> 17));
    acc8(acc, h1, h2f_bits(e0.y >> 17));
    acc8(acc, h2, h2f_bits(e0.z >> 17));
    acc8(acc, h3, h2f_bits(e0.w >> 17));
    i += 4;
  }
  for (; i < num; i++){
    u32 e = ewp[beg + i];
    acc8(acc, *(const uint4*)(H + ((size_t)(e & 0x1FFFFu) << 7) + (c8 << 3)), h2f_bits(e >> 17));
  }
  uint4 o;
  o.x = (u32)f2b(acc[0] * di) | ((u32)f2b(acc[1] * di) << 16);
  o.y = (u32)f2b(acc[2] * di) | ((u32)f2b(acc[3] * di) << 16);
  o.z = (u32)f2b(acc[4] * di) | ((u32)f2b(acc[5] * di) << 16);
  o.w = (u32)f2b(acc[6] * di) | ((u32)f2b(acc[7] * di) << 16);
  *(uint4*)(Y + ((size_t)node << 7) + (c8 << 3)) = o;
}

__global__ void k_agg40(const u16* __restrict__ H, const float* __restrict__ bout,
                        float* __restrict__ Y, const uint4* __restrict__ pm,
                        const u32* __restrict__ ewp, int n){
  int t = blockIdx.x * 256 + threadIdx.x;
  int g = t >> 4, c4 = t & 15;
  if (g >= n || c4 >= 10) return;
  uint4 m = pm[g];
  const int beg = (int)m.x, node = (int)m.y, num = (int)(m.z >> 16);
  const float di = h2f_bits(m.z & 0xFFFFu);
  float acc[4];
  {
    uint2 u = *(const uint2*)(H + (size_t)node * NOUT + (c4 << 2));
    acc[0] = b2f((u16)u.x) * di; acc[1] = b2f((u16)(u.x >> 16)) * di;
    acc[2] = b2f((u16)u.y) * di; acc[3] = b2f((u16)(u.y >> 16)) * di;
  }
  int i = 0;
  for (; i < num && ((beg + i) & 3); i++){
    u32 e = ewp[beg + i];
    acc4(acc, *(const uint2*)(H + (size_t)(e & 0x1FFFFu) * NOUT + (c4 << 2)), h2f_bits(e >> 17));
  }
  for (; i + 4 <= num; i += 4){
    uint4 e0 = *(const uint4*)(ewp + beg + i);
    uint2 a0 = *(const uint2*)(H + (size_t)(e0.x & 0x1FFFFu) * NOUT + (c4 << 2));
    uint2 a1 = *(const uint2*)(H + (size_t)(e0.y & 0x1FFFFu) * NOUT + (c4 << 2));
    uint2 a2 = *(const uint2*)(H + (size_t)(e0.z & 0x1FFFFu) * NOUT + (c4 << 2));
    uint2 a3 = *(const uint2*)(H + (size_t)(e0.w & 0x1FFFFu) * NOUT + (c4 << 2));
    acc4(acc, a0, h2f_bits(e0.x >> 17));
    acc4(acc, a1, h2f_bits(e0.y >> 17));
    acc4(acc, a2, h2f_bits(e0.z >> 17));
    acc4(acc, a3, h2f_bits(e0.w >> 17));
  }
  for (; i < num; i++){
    u32 e = ewp[beg + i];
    acc4(acc, *(const uint2*)(H + (size_t)(e & 0x1FFFFu) * NOUT + (c4 << 2)), h2f_bits(e >> 17));
  }
  float4 bb = *(const float4*)(bout + (c4 << 2));
  float4 o;
  o.x = fmaf(acc[0], di, bb.x); o.y = fmaf(acc[1], di, bb.y);
  o.z = fmaf(acc[2], di, bb.z); o.w = fmaf(acc[3], di, bb.w);
  *(float4*)(Y + (size_t)node * NOUT + (c4 << 2)) = o;
}

// ---------- BatchNorm stats (bf16 input, uint4 loads, 8-striped output) ----------
__global__ void k_bn_stats(const u16* __restrict__ X, float* __restrict__ sum8,
                           float* __restrict__ sq8, int n){
  const int tid = threadIdx.x;
  const int c8 = tid & 15, rl = tid >> 4;
  float s[8] = {0,0,0,0,0,0,0,0}, q[8] = {0,0,0,0,0,0,0,0};
  for (int r = blockIdx.x * 16 + rl; r < n; r += gridDim.x * 16){
    uint4 u = *(const uint4*)(X + ((size_t)r << 7) + (c8 << 3));
    float x0 = b2f((u16)u.x), x1 = b2f((u16)(u.x >> 16));
    float x2 = b2f((u16)u.y), x3 = b2f((u16)(u.y >> 16));
    float x4 = b2f((u16)u.z), x5 = b2f((u16)(u.z >> 16));
    float x6 = b2f((u16)u.w), x7 = b2f((u16)(u.w >> 16));
    s[0]+=x0; s[1]+=x1; s[2]+=x2; s[3]+=x3; s[4]+=x4; s[5]+=x5; s[6]+=x6; s[7]+=x7;
    q[0]=fmaf(x0,x0,q[0]); q[1]=fmaf(x1,x1,q[1]); q[2]=fmaf(x2,x2,q[2]); q[3]=fmaf(x3,x3,q[3]);
    q[4]=fmaf(x4,x4,q[4]); q[5]=fmaf(x5,x5,q[5]); q[6]=fmaf(x6,x6,q[6]); q[7]=fmaf(x7,x7,q[7]);
  }
  __shared__ float ls[256 * 8];
  const int sb = (blockIdx.x & 7) << 7;
  #pragma unroll
  for (int j = 0; j < 8; j++) ls[tid * 8 + j] = s[j];
  __syncthreads();
  if (tid < 128){
    float acc = 0.f;
    #pragma unroll
    for (int k = 0; k < 16; k++) acc += ls[(k << 7) + tid];
    atomicAdd(&sum8[sb + tid], acc);
  }
  __syncthreads();
  #pragma unroll
  for (int j = 0; j < 8; j++) ls[tid * 8 + j] = q[j];
  __syncthreads();
  if (tid < 128){
    float acc = 0.f;
    #pragma unroll
    for (int k = 0; k < 16; k++) acc += ls[(k << 7) + tid];
    atomicAdd(&sq8[sb + tid], acc);
  }
}

// ---------- launch ----------
extern "C" void kernel_launch(void* const* d_in, const int* in_sizes, int n_in,
                              void* d_out, int out_size, void* d_ws, size_t ws_size,
                              hipStream_t stream) {
  const float* x0        = (const float*)d_in[0];
  const float* x1        = (const float*)d_in[1];
  const int*   ei        = (const int*)  d_in[2];
  const float* W_init    = (const float*)d_in[3];
  const float* g_init    = (const float*)d_in[5];
  const float* beta_init = (const float*)d_in[6];
  const float* W_mid     = (const float*)d_in[7];
  const float* g_mid     = (const float*)d_in[9];
  const float* beta_mid  = (const float*)d_in[10];
  const float* W_out     = (const float*)d_in[11];
  const float* b_out     = (const float*)d_in[12];

  int N = in_sizes[0] / F_IN;
  int E = in_sizes[2] / 2;
  const int* esrc = ei;
  const int* edst = ei + E;
  int NR = (N + RSIZE - 1) >> RBITS;

  char* w = (char*)d_ws;
  size_t off = 0;
  auto take = [&](size_t bytes) -> char* {
    char* p = w + off;
    off = (off + bytes + 255) & ~(size_t)255;
    return p;
  };
  float* dinv      = (float*)take((size_t)N * 4);
  int4*  meta      = (int4*) take((size_t)N * 16);
  uint4* pm        = (uint4*)take((size_t)N * 16);
  // single zeroed block: rangecnt(512)|rangefill(512)|dhist(64)|dfill(64)|stats(4096)
  int*   zeroblk   = (int*)  take((size_t)5248 * 4);
  int*   rangecnt  = zeroblk;
  int*   rangefill = zeroblk + 512;
  int*   dhist     = zeroblk + 1024;
  int*   dfill     = zeroblk + 1088;
  float* stats     = (float*)(zeroblk + 1152);
  int*   rangebase = (int*)  take((size_t)MAXNR * 4);
  int*   dbase     = (int*)  take((size_t)DBINS * 4);
  int*   ebase     = (int*)  take((size_t)DBINS * 4);
  int*   ecapfill  = (int*)  take(64);
  u32*   part      = (u32*)  take((size_t)E * 4);
  int*   csr       = (int*)  take((size_t)E * 4);
  u32*   ewp       = (u32*)  take((size_t)E * 4);
  u16*   A         = (u16*)  take((size_t)N * 128 * 2);
  u16*   B         = (u16*)  take((size_t)N * 128 * 2);
  (void)ws_size; (void)n_in; (void)out_size;

  float* sum1 = stats;           // 8x128
  float* sq1  = stats + 1024;
  float* sum2 = stats + 2048;
  float* sq2  = stats + 3072;

  hipMemsetAsync(zeroblk, 0, (size_t)5248 * 4, stream);

  // CSR build via range partition (no global per-edge atomics)
  const int PB = 512;
  const int chunk = ceil_div_l(E, PB);
  const int NBn = ceil_div_l(N, 256);
  k_rangecount<<<PB, 256, 0, stream>>>(edst, rangecnt, E, NR, chunk);
  k_rangescan <<<1, MAXNR, 0, stream>>>(rangecnt, rangebase, NR);
  k_partition <<<PB, 256, 0, stream>>>(esrc, edst, rangebase, rangefill, part, E, NR, chunk);
  k_build     <<<NR, RSIZE, 0, stream>>>(part, rangecnt, rangebase, meta, dinv, csr, dhist, N);
  k_scan2     <<<1, 64, 0, stream>>>(dhist, dbase, ebase, ecapfill);
  k_degplace  <<<NBn, 256, 0, stream>>>(meta, dbase, ebase, dfill, ecapfill, pm, N);
  k_makeewp   <<<NBn, 256, 0, stream>>>(pm, csr, dinv, ewp, N);

  const int ntiles = ceil_div_l(N, 128);
  const int AGB = ceil_div_l(N, 16);       // agg blocks (16 nodes x 16 lanes)
  const size_t lds64  = (size_t)(128 * 136 + 64  * 136) * 2;  // 52224 B
  const size_t lds128 = (size_t)(128 * 136 + 128 * 136) * 2;  // 69632 B

  // layer 1: two branch GEMMs into concat layout
  k_gemm_mfma<64,false,false><<<768,256,lds64,stream>>>(x0, W_init,          64, 64,
      nullptr, nullptr, nullptr, nullptr, A, 128,  0, N, ntiles);
  k_gemm_mfma<64,false,false><<<768,256,lds64,stream>>>(x1, W_init + 128*64, 64, 64,
      nullptr, nullptr, nullptr, nullptr, A, 128, 64, N, ntiles);
  k_agg128<<<AGB,256,0,stream>>>(A, B, pm, ewp, N);
  k_bn_stats<<<512,256,0,stream>>>(B, sum1, sq1, N);

  // layer 2: single 128-col MFMA GEMM (bn_fin + BN1 + ReLU fused)
  k_gemm_mfma<128,true,true><<<512,256,lds128,stream>>>(B, W_mid, 128, 128,
      sum1, sq1, g_init, beta_init, A, 128, 0, N, ntiles);
  k_agg128<<<AGB,256,0,stream>>>(A, B, pm, ewp, N);
  k_bn_stats<<<512,256,0,stream>>>(B, sum2, sq2, N);

  // layer 3: bn_fin + BN2 + ReLU fused; 40 cols (zero-padded to 64), compact bf16 out
  k_gemm_mfma<64,true,true><<<768,256,lds64,stream>>>(B, W_out, 40, 40,
      sum2, sq2, g_mid, beta_mid, A, 40, 0, N, ntiles);
  k_agg40<<<AGB,256,0,stream>>>(A, b_out, (float*)d_out, pm, ewp, N);
}

// Round 11
// 349.658 us; speedup vs baseline: 1.3112x; 1.0091x over previous
//
#include <hip/hip_runtime.h>
#include <hip/hip_fp16.h>
#include <cstdint>
#include <cstddef>

#define F_IN 128
#define NOUT 40
#define BN_EPS 1e-5f
#define RBITS 8
#define RSIZE 256           // nodes per range
#define MAXNR 512           // supports N <= 131072
#define DBINS 64            // degree-sort bins (cap 63)

typedef unsigned short u16;
typedef unsigned int u32;
typedef __attribute__((ext_vector_type(8))) short short8v;  // 8 bf16 (4 VGPR)
typedef __attribute__((ext_vector_type(4))) float f32x4;

static inline int ceil_div_l(long a, long b){ return (int)((a + b - 1) / b); }

__device__ __forceinline__ float b2f(u16 h){
  union { u32 u; float f; } v; v.u = ((u32)h) << 16; return v.f;
}
__device__ __forceinline__ u16 f2b(float x){
  union { float f; u32 u; } v; v.f = x;
  u32 r = v.u + 0x7FFFu + ((v.u >> 16) & 1u);
  return (u16)(r >> 16);
}
__device__ __forceinline__ float h2f_bits(u32 bits){   // low 15 bits of fp16 (sign=0)
  return __half2float(__ushort_as_half((u16)bits));
}
__device__ __forceinline__ void acc8(float* acc, uint4 u, float w){
  acc[0] = fmaf(b2f((u16)u.x),         w, acc[0]);
  acc[1] = fmaf(b2f((u16)(u.x >> 16)), w, acc[1]);
  acc[2] = fmaf(b2f((u16)u.y),         w, acc[2]);
  acc[3] = fmaf(b2f((u16)(u.y >> 16)), w, acc[3]);
  acc[4] = fmaf(b2f((u16)u.z),         w, acc[4]);
  acc[5] = fmaf(b2f((u16)(u.z >> 16)), w, acc[5]);
  acc[6] = fmaf(b2f((u16)u.w),         w, acc[6]);
  acc[7] = fmaf(b2f((u16)(u.w >> 16)), w, acc[7]);
}
__device__ __forceinline__ void acc4(float* acc, uint2 u, float w){
  acc[0] = fmaf(b2f((u16)u.x),         w, acc[0]);
  acc[1] = fmaf(b2f((u16)(u.x >> 16)), w, acc[1]);
  acc[2] = fmaf(b2f((u16)u.y),         w, acc[2]);
  acc[3] = fmaf(b2f((u16)(u.y >> 16)), w, acc[3]);
}

// ---------- A1: per-range edge counts (LDS histogram) ----------
__global__ void k_rangecount(const int* __restrict__ dst, int* __restrict__ rangecnt,
                             int E, int NR, int chunk){
  __shared__ u32 hist[MAXNR];
  for (int i = threadIdx.x; i < NR; i += 256) hist[i] = 0;
  __syncthreads();
  int s = blockIdx.x * chunk;
  int e_end = min(s + chunk, E);
  for (int e = s + threadIdx.x; e < e_end; e += 256)
    atomicAdd(&hist[(u32)dst[e] >> RBITS], 1u);
  __syncthreads();
  for (int i = threadIdx.x; i < NR; i += 256){
    u32 h = hist[i];
    if (h) atomicAdd((u32*)&rangecnt[i], h);
  }
}

// ---------- A2: exclusive scan of range counts ----------
__global__ void k_rangescan(const int* __restrict__ rangecnt, int* __restrict__ rangebase,
                            int NR){
  __shared__ int s[MAXNR];
  int t = threadIdx.x;
  if (t < NR) s[t] = rangecnt[t];
  __syncthreads();
  if (t == 0){
    int acc = 0;
    for (int i = 0; i < NR; i++){ int v = s[i]; s[i] = acc; acc += v; }
  }
  __syncthreads();
  if (t < NR) rangebase[t] = s[t];
}

// ---------- A3: partition edges into per-range segments (packed u32) ----------
__global__ void k_partition(const int* __restrict__ src, const int* __restrict__ dst,
                            const int* __restrict__ rangebase, int* __restrict__ rangefill,
                            u32* __restrict__ part, int E, int NR, int chunk){
  __shared__ u32 hist[MAXNR];
  __shared__ u32 lbase[MAXNR];
  for (int i = threadIdx.x; i < NR; i += 256) hist[i] = 0;
  __syncthreads();
  int s0 = blockIdx.x * chunk;
  int e_end = min(s0 + chunk, E);
  for (int e = s0 + threadIdx.x; e < e_end; e += 256)
    atomicAdd(&hist[(u32)dst[e] >> RBITS], 1u);
  __syncthreads();
  for (int i = threadIdx.x; i < NR; i += 256){
    u32 h = hist[i];
    u32 b = h ? (u32)atomicAdd((u32*)&rangefill[i], h) : 0u;
    lbase[i] = (u32)rangebase[i] + b;
    hist[i] = 0;                       // reuse as local fill
  }
  __syncthreads();
  for (int e = s0 + threadIdx.x; e < e_end; e += 256){
    u32 d = (u32)dst[e];
    u32 r = d >> RBITS;
    u32 pos = lbase[r] + atomicAdd(&hist[r], 1u);
    part[pos] = (u32)src[e] | ((d & (RSIZE - 1)) << 17);
  }
}

// ---------- B: per-range CSR build + meta/dinv + degree histogram (LDS atomics) ----------
__global__ void k_build(const u32* __restrict__ part, const int* __restrict__ rangecnt,
                        const int* __restrict__ rangebase, int4* __restrict__ meta,
                        float* __restrict__ dinv, int* __restrict__ csr,
                        int* __restrict__ dhist, int n){
  __shared__ int hist[RSIZE];
  __shared__ int scanx[RSIZE];
  __shared__ int fill[RSIZE];
  __shared__ int ldh[DBINS];
  int r = blockIdx.x;
  int ne = rangecnt[r], base = rangebase[r];
  int t = threadIdx.x;
  hist[t] = 0;
  if (t < DBINS) ldh[t] = 0;
  __syncthreads();
  for (int i = t; i < ne; i += 256) atomicAdd(&hist[part[base + i] >> 17], 1);
  __syncthreads();
  int v = hist[t];
  scanx[t] = v;
  __syncthreads();
  for (int o = 1; o < 256; o <<= 1){
    int tv = (t >= o) ? scanx[t - o] : 0;
    __syncthreads();
    scanx[t] += tv;
    __syncthreads();
  }
  int excl = scanx[t] - v;
  int node = (r << RBITS) + t;
  if (node < n){
    float di = rsqrtf(1.0f + (float)v);
    meta[node] = make_int4(base + excl, v, __float_as_int(di), 0);
    dinv[node] = di;
    atomicAdd(&ldh[min(v, DBINS - 1)], 1);   // fused degree histogram
  }
  fill[t] = 0;
  scanx[t] = excl;
  __syncthreads();
  for (int i = t; i < ne; i += 256){
    u32 p = part[base + i];
    int dl = (int)(p >> 17);
    int pos = scanx[dl] + atomicAdd(&fill[dl], 1);
    csr[base + pos] = (int)(p & 0x1FFFFu);
  }
  if (t < DBINS && ldh[t]) atomicAdd(&dhist[t], ldh[t]);
}

// ---------- packed edge list (CSR order, coalesced): ewp[e] = fp16(dinv[src])<<17 | src ----------
// block 0 thread 0 also scans the degree histogram -> dbase
__global__ void k_makeew(const int* __restrict__ csr, const float* __restrict__ dinv,
                         u32* __restrict__ ewp, const int* __restrict__ dhist,
                         int* __restrict__ dbase, int E){
  int e = blockIdx.x * 256 + threadIdx.x;
  if (e < E){
    int s = csr[e];
    u32 hb = (u32)__half_as_ushort(__float2half(dinv[s]));
    ewp[e] = (u32)s | (hb << 17);
  }
  if (blockIdx.x == 0 && threadIdx.x == 0){
    int acc = 0;
    for (int i = 0; i < DBINS; i++){ dbase[i] = acc; acc += dhist[i]; }
  }
}

// ---------- degree-sorted placement: pm[pos] = (beg, node, num<<16|fp16(dinv), 0) ----------
__global__ void k_degplace(const int4* __restrict__ meta, const int* __restrict__ dbase,
                           int* __restrict__ dfill, uint4* __restrict__ pm, int n){
  __shared__ int h[DBINS], lbase[DBINS];
  if (threadIdx.x < DBINS) h[threadIdx.x] = 0;
  __syncthreads();
  int i = blockIdx.x * 256 + threadIdx.x;
  int d = 0; int4 m = make_int4(0,0,0,0);
  if (i < n){
    m = meta[i];
    d = min(m.y, DBINS - 1);
    atomicAdd(&h[d], 1);
  }
  __syncthreads();
  if (threadIdx.x < DBINS){
    int c = h[threadIdx.x];
    lbase[threadIdx.x] = c ? dbase[threadIdx.x] + atomicAdd(&dfill[threadIdx.x], c) : 0;
    h[threadIdx.x] = 0;
  }
  __syncthreads();
  if (i < n){
    int pos = lbase[d] + atomicAdd(&h[d], 1);
    float di = __int_as_float(m.z);
    u16 hb = __half_as_ushort(__float2half(di));
    pm[pos] = make_uint4((u32)m.x, (u32)i, ((u32)m.y << 16) | hb, 0u);
  }
}

// ---------- MFMA GEMM: 128-row x COLS tile, K=128, bf16 in/out, fp32 acc ----------
// BN=true: per-block prelude computes scale/shift from 8-striped raw sums (fused bn_fin).
template<int COLS, bool XBF, bool BN>
__launch_bounds__(256, 2)
__global__ void k_gemm_mfma(const void* __restrict__ Xv, const float* __restrict__ W,
                            int ldW, int wcols,
                            const float* __restrict__ bn_sum, const float* __restrict__ bn_sq,
                            const float* __restrict__ g, const float* __restrict__ beta,
                            u16* __restrict__ Y, int ldY, int col_off, int n, int ntiles){
  constexpr int NT = COLS / 16;          // col tiles per wave
  extern __shared__ u16 dyn_lds[];
  u16* Xl = dyn_lds;                     // [128][136]
  u16* Wt = dyn_lds + 128 * 136;         // [COLS][136]
  __shared__ float sc_l[128], sh_l[128];

  const int tid  = threadIdx.x;
  const int lane = tid & 63;
  const int wv   = tid >> 6;             // wave 0..3 -> rows wv*32..wv*32+31

  if (BN){
    if (tid < 128){
      float s = 0.f, q = 0.f;
      #pragma unroll
      for (int k = 0; k < 8; k++){ s += bn_sum[(k << 7) + tid]; q += bn_sq[(k << 7) + tid]; }
      float invn = 1.0f / (float)n;
      float mu  = s * invn;
      float var = q * invn - mu * mu;
      var = var > 0.f ? var : 0.f;
      float sc = g[tid] * rsqrtf(var + BN_EPS);
      sc_l[tid] = sc;
      sh_l[tid] = beta[tid] - mu * sc;
    }
    __syncthreads();
  }

  // stage W transposed (zero-pad cols >= wcols); wcols is a multiple of 4
  const int wf4 = wcols >> 2;
  for (int idx = tid; idx < 128 * (COLS >> 2); idx += 256){
    int k  = idx / (COLS >> 2);
    int c4 = idx % (COLS >> 2);
    float4 v = make_float4(0.f, 0.f, 0.f, 0.f);
    if (c4 < wf4) v = *(const float4*)(W + (size_t)k * ldW + (c4 << 2));
    int c = c4 << 2;
    Wt[(c    ) * 136 + k] = f2b(v.x);
    Wt[(c + 1) * 136 + k] = f2b(v.y);
    Wt[(c + 2) * 136 + k] = f2b(v.z);
    Wt[(c + 3) * 136 + k] = f2b(v.w);
  }

  float sc8[8], sh8[8];
  if (BN){
    int c0 = (tid & 15) << 3;
    #pragma unroll
    for (int j = 0; j < 8; j++){ sc8[j] = sc_l[c0 + j]; sh8[j] = sh_l[c0 + j]; }
  }

  const int frow = lane & 15;
  const int fk   = (lane >> 4) << 3;     // 0,8,16,24

  for (int t = blockIdx.x; t < ntiles; t += gridDim.x){
    const int r0 = t << 7;
    __syncthreads();   // protects Xl (prev readers) and covers Wt on first iter
    // stage X tile (bf16, optional fused BN+ReLU)
    for (int idx = tid; idx < 128 * 16; idx += 256){
      int row = idx >> 4, c8 = idx & 15;
      int gr = r0 + row;
      float x[8];
      if (gr < n){
        if (XBF){
          const u16* p = (const u16*)Xv + ((size_t)gr << 7) + (c8 << 3);
          uint4 u = *(const uint4*)p;
          x[0] = b2f((u16)u.x); x[1] = b2f((u16)(u.x >> 16));
          x[2] = b2f((u16)u.y); x[3] = b2f((u16)(u.y >> 16));
          x[4] = b2f((u16)u.z); x[5] = b2f((u16)(u.z >> 16));
          x[6] = b2f((u16)u.w); x[7] = b2f((u16)(u.w >> 16));
        } else {
          const float* p = (const float*)Xv + ((size_t)gr << 7) + (c8 << 3);
          float4 a = *(const float4*)p;
          float4 b = *(const float4*)(p + 4);
          x[0]=a.x; x[1]=a.y; x[2]=a.z; x[3]=a.w;
          x[4]=b.x; x[5]=b.y; x[6]=b.z; x[7]=b.w;
        }
        if (BN){
          #pragma unroll
          for (int j = 0; j < 8; j++)
            x[j] = fmaxf(fmaf(x[j], sc8[j], sh8[j]), 0.f);
        }
      } else {
        #pragma unroll
        for (int j = 0; j < 8; j++) x[j] = 0.f;
      }
      uint4 u;
      u.x = (u32)f2b(x[0]) | ((u32)f2b(x[1]) << 16);
      u.y = (u32)f2b(x[2]) | ((u32)f2b(x[3]) << 16);
      u.z = (u32)f2b(x[4]) | ((u32)f2b(x[5]) << 16);
      u.w = (u32)f2b(x[6]) | ((u32)f2b(x[7]) << 16);
      *(uint4*)(Xl + row * 136 + (c8 << 3)) = u;
    }
    __syncthreads();

    f32x4 acc[2][NT];
    #pragma unroll
    for (int i = 0; i < 2; i++)
      #pragma unroll
      for (int j = 0; j < NT; j++)
        acc[i][j] = (f32x4){0.f, 0.f, 0.f, 0.f};

    #pragma unroll
    for (int ks = 0; ks < 4; ks++){
      const int ko = (ks << 5) + fk;
      short8v a0 = *(const short8v*)(Xl + (wv * 32      + frow) * 136 + ko);
      short8v a1 = *(const short8v*)(Xl + (wv * 32 + 16 + frow) * 136 + ko);
      short8v b[NT];
      #pragma unroll
      for (int j = 0; j < NT; j++)
        b[j] = *(const short8v*)(Wt + (j * 16 + frow) * 136 + ko);
      #pragma unroll
      for (int j = 0; j < NT; j++){
        acc[0][j] = __builtin_amdgcn_mfma_f32_16x16x32_bf16(a0, b[j], acc[0][j], 0, 0, 0);
        acc[1][j] = __builtin_amdgcn_mfma_f32_16x16x32_bf16(a1, b[j], acc[1][j], 0, 0, 0);
      }
    }

    // store: D lane l -> col=l&15, rows (l>>4)*4+0..3 of each 16x16 tile
    #pragma unroll
    for (int i = 0; i < 2; i++){
      #pragma unroll
      for (int j = 0; j < NT; j++){
        int cbase = j * 16 + (lane & 15);
        if (cbase < wcols){
          int grow = r0 + wv * 32 + i * 16 + ((lane >> 4) << 2);
          #pragma unroll
          for (int r = 0; r < 4; r++){
            if (grow + r < n)
              Y[(size_t)(grow + r) * ldY + col_off + cbase] = f2b(acc[i][j][r]);
          }
        }
      }
    }
  }
}

// ---------- aggregation: 16 lanes/node, packed 4B edges, degree-sorted order ----------
__global__ void k_agg128(const u16* __restrict__ H, u16* __restrict__ Y,
                         const uint4* __restrict__ pm, const u32* __restrict__ ewp, int n){
  int t = blockIdx.x * 256 + threadIdx.x;
  int g = t >> 4, c8 = t & 15;
  if (g >= n) return;
  uint4 m = pm[g];
  const int beg = (int)m.x, node = (int)m.y, num = (int)(m.z >> 16);
  const float di = h2f_bits(m.z & 0xFFFFu);
  float acc[8];
  {
    uint4 u = *(const uint4*)(H + ((size_t)node << 7) + (c8 << 3));
    acc[0] = b2f((u16)u.x) * di; acc[1] = b2f((u16)(u.x >> 16)) * di;
    acc[2] = b2f((u16)u.y) * di; acc[3] = b2f((u16)(u.y >> 16)) * di;
    acc[4] = b2f((u16)u.z) * di; acc[5] = b2f((u16)(u.z >> 16)) * di;
    acc[6] = b2f((u16)u.w) * di; acc[7] = b2f((u16)(u.w >> 16)) * di;
  }
  int i = 0;
  // head: align (beg+i) to 4 for uint4 edge loads
  for (; i < num && ((beg + i) & 3); i++){
    u32 e = ewp[beg + i];
    acc8(acc, *(const uint4*)(H + ((size_t)(e & 0x1FFFFu) << 7) + (c8 << 3)), h2f_bits(e >> 17));
  }
  for (; i + 8 <= num; i += 8){
    uint4 e0 = *(const uint4*)(ewp + beg + i);
    uint4 e1 = *(const uint4*)(ewp + beg + i + 4);
    uint4 h0 = *(const uint4*)(H + ((size_t)(e0.x & 0x1FFFFu) << 7) + (c8 << 3));
    uint4 h1 = *(const uint4*)(H + ((size_t)(e0.y & 0x1FFFFu) << 7) + (c8 << 3));
    uint4 h2 = *(const uint4*)(H + ((size_t)(e0.z & 0x1FFFFu) << 7) + (c8 << 3));
    uint4 h3 = *(const uint4*)(H + ((size_t)(e0.w & 0x1FFFFu) << 7) + (c8 << 3));
    uint4 h4 = *(const uint4*)(H + ((size_t)(e1.x & 0x1FFFFu) << 7) + (c8 << 3));
    uint4 h5 = *(const uint4*)(H + ((size_t)(e1.y & 0x1FFFFu) << 7) + (c8 << 3));
    uint4 h6 = *(const uint4*)(H + ((size_t)(e1.z & 0x1FFFFu) << 7) + (c8 << 3));
    uint4 h7 = *(const uint4*)(H + ((size_t)(e1.w & 0x1FFFFu) << 7) + (c8 << 3));
    acc8(acc, h0, h2f_bits(e0.x >> 17));
    acc8(acc, h1, h2f_bits(e0.y >> 17));
    acc8(acc, h2, h2f_bits(e0.z >> 17));
    acc8(acc, h3, h2f_bits(e0.w >> 17));
    acc8(acc, h4, h2f_bits(e1.x >> 17));
    acc8(acc, h5, h2f_bits(e1.y >> 17));
    acc8(acc, h6, h2f_bits(e1.z >> 17));
    acc8(acc, h7, h2f_bits(e1.w >> 17));
  }
  if (i + 4 <= num){
    uint4 e0 = *(const uint4*)(ewp + beg + i);
    uint4 h0 = *(const uint4*)(H + ((size_t)(e0.x & 0x1FFFFu) << 7) + (c8 << 3));
    uint4 h1 = *(const uint4*)(H + ((size_t)(e0.y & 0x1FFFFu) << 7) + (c8 << 3));
    uint4 h2 = *(const uint4*)(H + ((size_t)(e0.z & 0x1FFFFu) << 7) + (c8 << 3));
    uint4 h3 = *(const uint4*)(H + ((size_t)(e0.w & 0x1FFFFu) << 7) + (c8 << 3));
    acc8(acc, h0, h2f_bits(e0.x >> 17));
    acc8(acc, h1, h2f_bits(e0.y >> 17));
    acc8(acc, h2, h2f_bits(e0.z >> 17));
    acc8(acc, h3, h2f_bits(e0.w >> 17));
    i += 4;
  }
  for (; i < num; i++){
    u32 e = ewp[beg + i];
    acc8(acc, *(const uint4*)(H + ((size_t)(e & 0x1FFFFu) << 7) + (c8 << 3)), h2f_bits(e >> 17));
  }
  uint4 o;
  o.x = (u32)f2b(acc[0] * di) | ((u32)f2b(acc[1] * di) << 16);
  o.y = (u32)f2b(acc[2] * di) | ((u32)f2b(acc[3] * di) << 16);
  o.z = (u32)f2b(acc[4] * di) | ((u32)f2b(acc[5] * di) << 16);
  o.w = (u32)f2b(acc[6] * di) | ((u32)f2b(acc[7] * di) << 16);
  *(uint4*)(Y + ((size_t)node << 7) + (c8 << 3)) = o;
}

__global__ void k_agg40(const u16* __restrict__ H, const float* __restrict__ bout,
                        float* __restrict__ Y, const uint4* __restrict__ pm,
                        const u32* __restrict__ ewp, int n){
  int t = blockIdx.x * 256 + threadIdx.x;
  int g = t >> 4, c4 = t & 15;
  if (g >= n || c4 >= 10) return;
  uint4 m = pm[g];
  const int beg = (int)m.x, node = (int)m.y, num = (int)(m.z >> 16);
  const float di = h2f_bits(m.z & 0xFFFFu);
  float acc[4];
  {
    uint2 u = *(const uint2*)(H + (size_t)node * NOUT + (c4 << 2));
    acc[0] = b2f((u16)u.x) * di; acc[1] = b2f((u16)(u.x >> 16)) * di;
    acc[2] = b2f((u16)u.y) * di; acc[3] = b2f((u16)(u.y >> 16)) * di;
  }
  int i = 0;
  for (; i < num && ((beg + i) & 3); i++){
    u32 e = ewp[beg + i];
    acc4(acc, *(const uint2*)(H + (size_t)(e & 0x1FFFFu) * NOUT + (c4 << 2)), h2f_bits(e >> 17));
  }
  for (; i + 4 <= num; i += 4){
    uint4 e0 = *(const uint4*)(ewp + beg + i);
    uint2 a0 = *(const uint2*)(H + (size_t)(e0.x & 0x1FFFFu) * NOUT + (c4 << 2));
    uint2 a1 = *(const uint2*)(H + (size_t)(e0.y & 0x1FFFFu) * NOUT + (c4 << 2));
    uint2 a2 = *(const uint2*)(H + (size_t)(e0.z & 0x1FFFFu) * NOUT + (c4 << 2));
    uint2 a3 = *(const uint2*)(H + (size_t)(e0.w & 0x1FFFFu) * NOUT + (c4 << 2));
    acc4(acc, a0, h2f_bits(e0.x >> 17));
    acc4(acc, a1, h2f_bits(e0.y >> 17));
    acc4(acc, a2, h2f_bits(e0.z >> 17));
    acc4(acc, a3, h2f_bits(e0.w >> 17));
  }
  for (; i < num; i++){
    u32 e = ewp[beg + i];
    acc4(acc, *(const uint2*)(H + (size_t)(e & 0x1FFFFu) * NOUT + (c4 << 2)), h2f_bits(e >> 17));
  }
  float4 bb = *(const float4*)(bout + (c4 << 2));
  float4 o;
  o.x = fmaf(acc[0], di, bb.x); o.y = fmaf(acc[1], di, bb.y);
  o.z = fmaf(acc[2], di, bb.z); o.w = fmaf(acc[3], di, bb.w);
  *(float4*)(Y + (size_t)node * NOUT + (c4 << 2)) = o;
}

// ---------- BatchNorm stats (bf16 input, uint4 loads, 8-striped output) ----------
__global__ void k_bn_stats(const u16* __restrict__ X, float* __restrict__ sum8,
                           float* __restrict__ sq8, int n){
  const int tid = threadIdx.x;
  const int c8 = tid & 15, rl = tid >> 4;
  float s[8] = {0,0,0,0,0,0,0,0}, q[8] = {0,0,0,0,0,0,0,0};
  for (int r = blockIdx.x * 16 + rl; r < n; r += gridDim.x * 16){
    uint4 u = *(const uint4*)(X + ((size_t)r << 7) + (c8 << 3));
    float x0 = b2f((u16)u.x), x1 = b2f((u16)(u.x >> 16));
    float x2 = b2f((u16)u.y), x3 = b2f((u16)(u.y >> 16));
    float x4 = b2f((u16)u.z), x5 = b2f((u16)(u.z >> 16));
    float x6 = b2f((u16)u.w), x7 = b2f((u16)(u.w >> 16));
    s[0]+=x0; s[1]+=x1; s[2]+=x2; s[3]+=x3; s[4]+=x4; s[5]+=x5; s[6]+=x6; s[7]+=x7;
    q[0]=fmaf(x0,x0,q[0]); q[1]=fmaf(x1,x1,q[1]); q[2]=fmaf(x2,x2,q[2]); q[3]=fmaf(x3,x3,q[3]);
    q[4]=fmaf(x4,x4,q[4]); q[5]=fmaf(x5,x5,q[5]); q[6]=fmaf(x6,x6,q[6]); q[7]=fmaf(x7,x7,q[7]);
  }
  __shared__ float ls[256 * 8];
  const int sb = (blockIdx.x & 7) << 7;
  #pragma unroll
  for (int j = 0; j < 8; j++) ls[tid * 8 + j] = s[j];
  __syncthreads();
  if (tid < 128){
    float acc = 0.f;
    #pragma unroll
    for (int k = 0; k < 16; k++) acc += ls[(k << 7) + tid];
    atomicAdd(&sum8[sb + tid], acc);
  }
  __syncthreads();
  #pragma unroll
  for (int j = 0; j < 8; j++) ls[tid * 8 + j] = q[j];
  __syncthreads();
  if (tid < 128){
    float acc = 0.f;
    #pragma unroll
    for (int k = 0; k < 16; k++) acc += ls[(k << 7) + tid];
    atomicAdd(&sq8[sb + tid], acc);
  }
}

// ---------- launch ----------
extern "C" void kernel_launch(void* const* d_in, const int* in_sizes, int n_in,
                              void* d_out, int out_size, void* d_ws, size_t ws_size,
                              hipStream_t stream) {
  const float* x0        = (const float*)d_in[0];
  const float* x1        = (const float*)d_in[1];
  const int*   ei        = (const int*)  d_in[2];
  const float* W_init    = (const float*)d_in[3];
  const float* g_init    = (const float*)d_in[5];
  const float* beta_init = (const float*)d_in[6];
  const float* W_mid     = (const float*)d_in[7];
  const float* g_mid     = (const float*)d_in[9];
  const float* beta_mid  = (const float*)d_in[10];
  const float* W_out     = (const float*)d_in[11];
  const float* b_out     = (const float*)d_in[12];

  int N = in_sizes[0] / F_IN;
  int E = in_sizes[2] / 2;
  const int* esrc = ei;
  const int* edst = ei + E;
  int NR = (N + RSIZE - 1) >> RBITS;

  char* w = (char*)d_ws;
  size_t off = 0;
  auto take = [&](size_t bytes) -> char* {
    char* p = w + off;
    off = (off + bytes + 255) & ~(size_t)255;
    return p;
  };
  float* dinv      = (float*)take((size_t)N * 4);
  int4*  meta      = (int4*) take((size_t)N * 16);
  uint4* pm        = (uint4*)take((size_t)N * 16);
  // single zeroed block: rangecnt(512)|rangefill(512)|dhist(64)|dfill(64)|stats(4096)
  int*   zeroblk   = (int*)  take((size_t)5248 * 4);
  int*   rangecnt  = zeroblk;
  int*   rangefill = zeroblk + 512;
  int*   dhist     = zeroblk + 1024;
  int*   dfill     = zeroblk + 1088;
  float* stats     = (float*)(zeroblk + 1152);
  int*   rangebase = (int*)  take((size_t)MAXNR * 4);
  int*   dbase     = (int*)  take((size_t)DBINS * 4);
  u32*   part      = (u32*)  take((size_t)E * 4);
  int*   csr       = (int*)  take((size_t)E * 4);
  u32*   ewp       = (u32*)  take((size_t)E * 4);
  u16*   A         = (u16*)  take((size_t)N * 128 * 2);
  u16*   B         = (u16*)  take((size_t)N * 128 * 2);
  (void)ws_size; (void)n_in; (void)out_size;

  float* sum1 = stats;           // 8x128
  float* sq1  = stats + 1024;
  float* sum2 = stats + 2048;
  float* sq2  = stats + 3072;

  hipMemsetAsync(zeroblk, 0, (size_t)5248 * 4, stream);

  // CSR build via range partition (no global per-edge atomics)
  const int PB = 512;
  const int chunk = ceil_div_l(E, PB);
  const int NBn = ceil_div_l(N, 256);
  k_rangecount<<<PB, 256, 0, stream>>>(edst, rangecnt, E, NR, chunk);
  k_rangescan <<<1, MAXNR, 0, stream>>>(rangecnt, rangebase, NR);
  k_partition <<<PB, 256, 0, stream>>>(esrc, edst, rangebase, rangefill, part, E, NR, chunk);
  k_build     <<<NR, RSIZE, 0, stream>>>(part, rangecnt, rangebase, meta, dinv, csr, dhist, N);
  k_makeew    <<<ceil_div_l(E,256), 256, 0, stream>>>(csr, dinv, ewp, dhist, dbase, E);
  k_degplace  <<<NBn, 256, 0, stream>>>(meta, dbase, dfill, pm, N);

  const int ntiles = ceil_div_l(N, 128);
  const int AGB = ceil_div_l(N, 16);       // agg blocks (16 nodes x 16 lanes)
  const size_t lds64  = (size_t)(128 * 136 + 64  * 136) * 2;  // 52224 B
  const size_t lds128 = (size_t)(128 * 136 + 128 * 136) * 2;  // 69632 B

  // layer 1: two branch GEMMs into concat layout
  k_gemm_mfma<64,false,false><<<768,256,lds64,stream>>>(x0, W_init,          64, 64,
      nullptr, nullptr, nullptr, nullptr, A, 128,  0, N, ntiles);
  k_gemm_mfma<64,false,false><<<768,256,lds64,stream>>>(x1, W_init + 128*64, 64, 64,
      nullptr, nullptr, nullptr, nullptr, A, 128, 64, N, ntiles);
  k_agg128<<<AGB,256,0,stream>>>(A, B, pm, ewp, N);
  k_bn_stats<<<512,256,0,stream>>>(B, sum1, sq1, N);

  // layer 2: single 128-col MFMA GEMM (bn_fin + BN1 + ReLU fused)
  k_gemm_mfma<128,true,true><<<512,256,lds128,stream>>>(B, W_mid, 128, 128,
      sum1, sq1, g_init, beta_init, A, 128, 0, N, ntiles);
  k_agg128<<<AGB,256,0,stream>>>(A, B, pm, ewp, N);
  k_bn_stats<<<512,256,0,stream>>>(B, sum2, sq2, N);

  // layer 3: bn_fin + BN2 + ReLU fused; 40 cols (zero-padded to 64), compact bf16 out
  k_gemm_mfma<64,true,true><<<768,256,lds64,stream>>>(B, W_out, 40, 40,
      sum2, sq2, g_mid, beta_mid, A, 40, 0, N, ntiles);
  k_agg40<<<AGB,256,0,stream>>>(A, b_out, (float*)d_out, pm, ewp, N);
}